// Round 1
// baseline (961.908 us; speedup 1.0000x reference)
//
#include <hip/hip_runtime.h>

#define DIM 128

// ---------------- setup kernels ----------------

__global__ void k_deg_cnt(const int* __restrict__ row, const int* __restrict__ col,
                          float* __restrict__ deg, int* __restrict__ cnt, int E) {
    int e = blockIdx.x * blockDim.x + threadIdx.x;
    if (e < E) {
        atomicAdd(&deg[col[e]], 1.0f);
        atomicAdd(&cnt[row[e]], 1);
    }
}

__global__ void k_dis(const float* __restrict__ deg, float* __restrict__ dis, int N) {
    int i = blockIdx.x * blockDim.x + threadIdx.x;
    if (i < N) {
        float d = deg[i];
        dis[i] = d > 0.f ? rsqrtf(d) : 0.f;
    }
}

__global__ __launch_bounds__(1024) void k_scan(const int* __restrict__ cnt, int* __restrict__ csr, int N) {
    __shared__ int part[1024];
    int tid = threadIdx.x;
    int per = (N + 1023) / 1024;
    int s0 = tid * per;
    int sum = 0;
    for (int i = 0; i < per; i++) {
        int idx = s0 + i;
        if (idx < N) sum += cnt[idx];
    }
    part[tid] = sum;
    __syncthreads();
    for (int off = 1; off < 1024; off <<= 1) {
        int v = (tid >= off) ? part[tid - off] : 0;
        __syncthreads();
        part[tid] += v;
        __syncthreads();
    }
    int run = (tid == 0) ? 0 : part[tid - 1];
    for (int i = 0; i < per; i++) {
        int idx = s0 + i;
        if (idx < N) { csr[idx] = run; run += cnt[idx]; }
    }
    if (tid == 1023) csr[N] = part[1023];
}

__global__ void k_scatter(const int* __restrict__ row, const int* __restrict__ col,
                          const int* __restrict__ et, const float* __restrict__ ew,
                          const float* __restrict__ dis, const int* __restrict__ csr,
                          int* __restrict__ fill, int* __restrict__ packed,
                          float* __restrict__ snorm, int E) {
    int e = blockIdx.x * blockDim.x + threadIdx.x;
    if (e < E) {
        int r = row[e], c = col[e];
        int pos = csr[r] + atomicAdd(&fill[r], 1);
        packed[pos] = c | (et[e] << 16);          // c < 65536 (N=50000)
        snorm[pos] = dis[r] * dis[c] * ew[e];
    }
}

// ---------------- aggregation: agg[n][t*128+i] = sum norm * x[col][i] ----------------
// one wave (64 lanes) per node; float2 per lane covers 128 cols; 4 type accumulators in regs

__global__ __launch_bounds__(256) void k_agg(const float* __restrict__ x, const int* __restrict__ csr,
                                             const int* __restrict__ packed, const float* __restrict__ snorm,
                                             float* __restrict__ agg, int n0, int n1) {
    int wid = threadIdx.x >> 6;
    int lane = threadIdx.x & 63;
    int n = n0 + blockIdx.x * 4 + wid;
    if (n >= n1) return;
    float2 a0 = {0.f, 0.f}, a1 = {0.f, 0.f}, a2 = {0.f, 0.f}, a3 = {0.f, 0.f};
    int s = csr[n], e = csr[n + 1];
    for (int j = s; j < e; j++) {
        int p = packed[j];
        float wgt = snorm[j];
        int c = p & 0xFFFF;
        int t = p >> 16;
        float2 v = *(const float2*)(x + (size_t)c * DIM + lane * 2);
        v.x *= wgt; v.y *= wgt;
        if (t == 0)      { a0.x += v.x; a0.y += v.y; }
        else if (t == 1) { a1.x += v.x; a1.y += v.y; }
        else if (t == 2) { a2.x += v.x; a2.y += v.y; }
        else             { a3.x += v.x; a3.y += v.y; }
    }
    float* dst = agg + (size_t)(n - n0) * 512;
    *(float2*)(dst + 0 * DIM + lane * 2) = a0;
    *(float2*)(dst + 1 * DIM + lane * 2) = a1;
    *(float2*)(dst + 2 * DIM + lane * 2) = a2;
    *(float2*)(dst + 3 * DIM + lane * 2) = a3;
}

// ---------------- GEMM: C[rows,128] = leaky(A[rows,512] @ B[512,128] + bias), fused final combine ----------------

template <int MODE>
__global__ __launch_bounds__(256) void k_gemm(const float* __restrict__ A, const float* __restrict__ B,
                                              const float* __restrict__ bias,
                                              const float* __restrict__ x0, const float* __restrict__ zz1,
                                              const float* __restrict__ zz2,
                                              float* __restrict__ C, int n0, int rows_total) {
    __shared__ float As[64][33];
    __shared__ float Bs[32][128];
    int tid = threadIdx.x;
    int m_block = blockIdx.x * 64;
    int tn = tid & 15;   // col group of 8
    int tm = tid >> 4;   // row group of 4
    float acc[4][8] = {};
    int lr = tid >> 3;          // 0..31 row within half-tile
    int lc = (tid & 7) * 4;     // float4 col within k-tile

    for (int k0 = 0; k0 < 512; k0 += 32) {
        // A tile 64x32 (guarded)
        #pragma unroll
        for (int rr = 0; rr < 2; rr++) {
            int m = m_block + lr + rr * 32;
            float4 v = {0.f, 0.f, 0.f, 0.f};
            if (m < rows_total) v = *(const float4*)(A + (size_t)m * 512 + k0 + lc);
            As[lr + rr * 32][lc + 0] = v.x;
            As[lr + rr * 32][lc + 1] = v.y;
            As[lr + rr * 32][lc + 2] = v.z;
            As[lr + rr * 32][lc + 3] = v.w;
        }
        // B tile 32x128 (contiguous)
        {
            const float4* src = (const float4*)(B + (size_t)k0 * 128);
            float4* dst = (float4*)(&Bs[0][0]);
            dst[tid]       = src[tid];
            dst[tid + 256] = src[tid + 256];
            dst[tid + 512] = src[tid + 512];
            dst[tid + 768] = src[tid + 768];
        }
        __syncthreads();
        #pragma unroll
        for (int k = 0; k < 32; k++) {
            float a0 = As[tm * 4 + 0][k];
            float a1 = As[tm * 4 + 1][k];
            float a2 = As[tm * 4 + 2][k];
            float a3 = As[tm * 4 + 3][k];
            float b[8];
            #pragma unroll
            for (int j = 0; j < 8; j++) b[j] = Bs[k][tn * 8 + j];
            #pragma unroll
            for (int j = 0; j < 8; j++) {
                acc[0][j] += a0 * b[j];
                acc[1][j] += a1 * b[j];
                acc[2][j] += a2 * b[j];
                acc[3][j] += a3 * b[j];
            }
        }
        __syncthreads();
    }
    #pragma unroll
    for (int i = 0; i < 4; i++) {
        int m = m_block + tm * 4 + i;
        if (m >= rows_total) break;
        size_t gr = (size_t)(n0 + m) * DIM + tn * 8;
        #pragma unroll
        for (int j = 0; j < 8; j++) {
            float v = acc[i][j] + bias[tn * 8 + j];
            v = v > 0.f ? v : 0.01f * v;
            if (MODE == 1) v = 0.25f * (x0[gr + j] + zz1[gr + j] + zz2[gr + j] + v);
            C[gr + j] = v;
        }
    }
}

// ---------------- launch ----------------

extern "C" void kernel_launch(void* const* d_in, const int* in_sizes, int n_in,
                              void* d_out, int out_size, void* d_ws, size_t ws_size,
                              hipStream_t stream) {
    const float* x     = (const float*)d_in[0];
    const int*   eidx  = (const int*)d_in[1];
    const int*   etype = (const int*)d_in[2];
    const float* eattr = (const float*)d_in[3];
    const float* W1 = (const float*)d_in[4];
    const float* b1 = (const float*)d_in[5];
    const float* W2 = (const float*)d_in[6];
    const float* b2 = (const float*)d_in[7];
    const float* W3 = (const float*)d_in[8];
    const float* b3 = (const float*)d_in[9];

    const int E = in_sizes[2];
    const int N = in_sizes[0] / DIM;
    const int* row = eidx;
    const int* col = eidx + E;

    char* w = (char*)d_ws;
    size_t off = 0;
    auto alloc = [&](size_t bytes) { size_t o = off; off = (off + bytes + 255) & ~255ULL; return o; };
    float* deg    = (float*)(w + alloc((size_t)N * 4));
    float* dis    = (float*)(w + alloc((size_t)N * 4));
    int*   cnt    = (int*)(w + alloc((size_t)N * 4));
    int*   fill   = (int*)(w + alloc((size_t)N * 4));
    int*   csr    = (int*)(w + alloc((size_t)(N + 1) * 4));
    int*   packed = (int*)(w + alloc((size_t)E * 4));
    float* snorm  = (float*)(w + alloc((size_t)E * 4));
    float* z1     = (float*)(w + alloc((size_t)N * DIM * 4));
    float* z2     = (float*)(w + alloc((size_t)N * DIM * 4));
    size_t remain = ws_size > off ? ws_size - off : 0;
    long long chunk_ll = (long long)(remain / 2048);   // bytes per agg row = 512*4
    int chunk = chunk_ll > N ? N : (int)chunk_ll;
    chunk &= ~63;
    if (chunk < 64) chunk = 64;
    float* agg = (float*)(w + off);

    hipMemsetAsync(deg, 0, (size_t)N * 4, stream);
    hipMemsetAsync(cnt, 0, (size_t)N * 4, stream);
    hipMemsetAsync(fill, 0, (size_t)N * 4, stream);

    k_deg_cnt<<<(E + 255) / 256, 256, 0, stream>>>(row, col, deg, cnt, E);
    k_dis<<<(N + 255) / 256, 256, 0, stream>>>(deg, dis, N);
    k_scan<<<1, 1024, 0, stream>>>(cnt, csr, N);
    k_scatter<<<(E + 255) / 256, 256, 0, stream>>>(row, col, etype, eattr, dis, csr, fill, packed, snorm, E);

    const float* Ws[3]  = {W1, W2, W3};
    const float* bs[3]  = {b1, b2, b3};
    const float* xin[3] = {x, z1, z2};
    float* zout[3]      = {z1, z2, (float*)d_out};

    for (int L = 0; L < 3; L++) {
        for (int n0 = 0; n0 < N; n0 += chunk) {
            int rows = (N - n0) < chunk ? (N - n0) : chunk;
            k_agg<<<(rows + 3) / 4, 256, 0, stream>>>(xin[L], csr, packed, snorm, agg, n0, n0 + rows);
            if (L < 2)
                k_gemm<0><<<(rows + 63) / 64, 256, 0, stream>>>(agg, Ws[L], bs[L],
                                                                nullptr, nullptr, nullptr,
                                                                zout[L], n0, rows);
            else
                k_gemm<1><<<(rows + 63) / 64, 256, 0, stream>>>(agg, Ws[L], bs[L],
                                                                x, z1, z2,
                                                                zout[L], n0, rows);
        }
    }
}

// Round 2
// 652.317 us; speedup vs baseline: 1.4746x; 1.4746x over previous
//
#include <hip/hip_runtime.h>

#define DIM 128

typedef __attribute__((ext_vector_type(8))) short bf16x8;
typedef __attribute__((ext_vector_type(4))) float f32x4;

__device__ __forceinline__ float bf2f(unsigned int u) {
    return __builtin_bit_cast(float, u << 16);
}
__device__ __forceinline__ unsigned short f2bf(float f) {
    unsigned int u = __builtin_bit_cast(unsigned int, f);
    u = (u + 0x7FFFu + ((u >> 16) & 1u)) >> 16;   // RNE
    return (unsigned short)u;
}

// ---------------- setup kernels ----------------

__global__ void k_deg_cnt(const int* __restrict__ row, const int* __restrict__ col,
                          float* __restrict__ deg, int* __restrict__ cnt, int E) {
    int e = blockIdx.x * blockDim.x + threadIdx.x;
    if (e < E) {
        atomicAdd(&deg[col[e]], 1.0f);
        atomicAdd(&cnt[row[e]], 1);
    }
}

__global__ void k_dis(const float* __restrict__ deg, float* __restrict__ dis, int N) {
    int i = blockIdx.x * blockDim.x + threadIdx.x;
    if (i < N) {
        float d = deg[i];
        dis[i] = d > 0.f ? rsqrtf(d) : 0.f;
    }
}

__global__ __launch_bounds__(1024) void k_scan(const int* __restrict__ cnt, int* __restrict__ csr, int N) {
    __shared__ int part[1024];
    int tid = threadIdx.x;
    int per = (N + 1023) / 1024;
    int s0 = tid * per;
    int sum = 0;
    for (int i = 0; i < per; i++) {
        int idx = s0 + i;
        if (idx < N) sum += cnt[idx];
    }
    part[tid] = sum;
    __syncthreads();
    for (int off = 1; off < 1024; off <<= 1) {
        int v = (tid >= off) ? part[tid - off] : 0;
        __syncthreads();
        part[tid] += v;
        __syncthreads();
    }
    int run = (tid == 0) ? 0 : part[tid - 1];
    for (int i = 0; i < per; i++) {
        int idx = s0 + i;
        if (idx < N) { csr[idx] = run; run += cnt[idx]; }
    }
    if (tid == 1023) csr[N] = part[1023];
}

__global__ void k_scatter(const int* __restrict__ row, const int* __restrict__ col,
                          const int* __restrict__ et, const float* __restrict__ ew,
                          const float* __restrict__ dis, const int* __restrict__ csr,
                          int* __restrict__ fill, int* __restrict__ packed,
                          float* __restrict__ snorm, int E) {
    int e = blockIdx.x * blockDim.x + threadIdx.x;
    if (e < E) {
        int r = row[e], c = col[e];
        int pos = csr[r] + atomicAdd(&fill[r], 1);
        packed[pos] = c | (et[e] << 16);          // c < 65536 (N=50000)
        snorm[pos] = dis[r] * dis[c] * ew[e];
    }
}

// fp32 -> bf16 node features (x only; z1b/z2b come from GEMM epilogue)
__global__ void k_xb(const float* __restrict__ in, unsigned short* __restrict__ out, int total4) {
    int i = blockIdx.x * blockDim.x + threadIdx.x;
    if (i < total4) {
        float4 v = ((const float4*)in)[i];
        ushort4 o;
        o.x = f2bf(v.x); o.y = f2bf(v.y); o.z = f2bf(v.z); o.w = f2bf(v.w);
        ((ushort4*)out)[i] = o;
    }
}

// Wt[n][k] = W[k>>7][k&127][n], bf16. out: [128][512]
__global__ void k_wt(const float* __restrict__ W, unsigned short* __restrict__ Wt) {
    int o = blockIdx.x * blockDim.x + threadIdx.x;   // 65536
    int n = o >> 9, k = o & 511;
    int t = k >> 7, i = k & 127;
    Wt[o] = f2bf(W[t * 16384 + i * 128 + n]);
}

// ---------------- aggregation (bf16 gather, fp32 accum, bf16 agg out) ----------------
// one wave per node; 2 cols/lane; agg[n][t*128+i]

__global__ __launch_bounds__(256) void k_agg(const unsigned short* __restrict__ xb,
                                             const int* __restrict__ csr,
                                             const int* __restrict__ packed,
                                             const float* __restrict__ snorm,
                                             unsigned short* __restrict__ agg, int N) {
    int wid = threadIdx.x >> 6;
    int lane = threadIdx.x & 63;
    int n = blockIdx.x * 4 + wid;
    if (n >= N) return;
    float2 a0 = {0.f, 0.f}, a1 = {0.f, 0.f}, a2 = {0.f, 0.f}, a3 = {0.f, 0.f};
    int s = csr[n], e = csr[n + 1];
    const unsigned short* xcol = xb + lane * 2;
    for (int j = s; j < e; j++) {
        int p = packed[j];
        float wgt = snorm[j];
        int c = p & 0xFFFF;
        int t = (p >> 16) & 3;
        unsigned int v = *(const unsigned int*)(xcol + (size_t)c * DIM);
        float v0 = bf2f(v & 0xFFFFu) * wgt;
        float v1 = bf2f(v >> 16) * wgt;
        if (t == 0)      { a0.x += v0; a0.y += v1; }
        else if (t == 1) { a1.x += v0; a1.y += v1; }
        else if (t == 2) { a2.x += v0; a2.y += v1; }
        else             { a3.x += v0; a3.y += v1; }
    }
    unsigned int* dst = (unsigned int*)(agg + (size_t)n * 512) + lane;
    dst[0]   = (unsigned int)f2bf(a0.x) | ((unsigned int)f2bf(a0.y) << 16);
    dst[64]  = (unsigned int)f2bf(a1.x) | ((unsigned int)f2bf(a1.y) << 16);
    dst[128] = (unsigned int)f2bf(a2.x) | ((unsigned int)f2bf(a2.y) << 16);
    dst[192] = (unsigned int)f2bf(a3.x) | ((unsigned int)f2bf(a3.y) << 16);
}

// ---------------- MFMA GEMM: C[rows,128] = leaky(A[rows,512] @ Wt^T + bias) ----------------
// A: bf16 row-major [rows][512]; Wt: bf16 [128 cols][512 k]
// wave: 16 rows x 128 cols; block: 4 waves = 64 rows. No LDS.

template <int MODE>
__global__ __launch_bounds__(256) void k_gemm(const unsigned short* __restrict__ A,
                                              const unsigned short* __restrict__ Bt,
                                              const float* __restrict__ bias,
                                              const float* __restrict__ x0,
                                              const float* __restrict__ z1f,
                                              const float* __restrict__ z2f,
                                              float* __restrict__ Cf,
                                              unsigned short* __restrict__ Cb,
                                              int rows) {
    int wid = threadIdx.x >> 6;
    int lane = threadIdx.x & 63;
    int row0 = blockIdx.x * 64 + wid * 16;
    if (row0 >= rows) return;
    int lr = lane & 15;        // A-row / B-col within tile
    int lk = lane >> 4;        // k sub-block 0..3

    int arow = row0 + lr;
    if (arow >= rows) arow = rows - 1;
    const unsigned short* Abase = A + (size_t)arow * 512 + lk * 8;
    const unsigned short* Bbase = Bt + (size_t)lr * 512 + lk * 8;

    f32x4 acc[8] = {};
    #pragma unroll
    for (int k0 = 0; k0 < 512; k0 += 32) {
        bf16x8 af = *(const bf16x8*)(Abase + k0);
        #pragma unroll
        for (int ct = 0; ct < 8; ct++) {
            bf16x8 bf = *(const bf16x8*)(Bbase + (size_t)ct * 16 * 512 + k0);
            acc[ct] = __builtin_amdgcn_mfma_f32_16x16x32_bf16(af, bf, acc[ct], 0, 0, 0);
        }
    }

    // epilogue: C/D layout col=lane&15, row=(lane>>4)*4+reg
    #pragma unroll
    for (int ct = 0; ct < 8; ct++) {
        int col = ct * 16 + lr;
        float bv = bias[col];
        #pragma unroll
        for (int r = 0; r < 4; r++) {
            int rowv = row0 + lk * 4 + r;
            if (rowv < rows) {
                size_t idx = (size_t)rowv * DIM + col;
                float v = acc[ct][r] + bv;
                v = v > 0.f ? v : 0.01f * v;
                if (MODE == 1) {
                    v = 0.25f * (x0[idx] + z1f[idx] + z2f[idx] + v);
                    Cf[idx] = v;
                } else {
                    Cf[idx] = v;
                    Cb[idx] = f2bf(v);
                }
            }
        }
    }
}

// ---------------- launch ----------------

extern "C" void kernel_launch(void* const* d_in, const int* in_sizes, int n_in,
                              void* d_out, int out_size, void* d_ws, size_t ws_size,
                              hipStream_t stream) {
    const float* x     = (const float*)d_in[0];
    const int*   eidx  = (const int*)d_in[1];
    const int*   etype = (const int*)d_in[2];
    const float* eattr = (const float*)d_in[3];
    const float* W1 = (const float*)d_in[4];
    const float* b1 = (const float*)d_in[5];
    const float* W2 = (const float*)d_in[6];
    const float* b2 = (const float*)d_in[7];
    const float* W3 = (const float*)d_in[8];
    const float* b3 = (const float*)d_in[9];

    const int E = in_sizes[2];
    const int N = in_sizes[0] / DIM;
    const int* row = eidx;
    const int* col = eidx + E;

    char* w = (char*)d_ws;
    size_t off = 0;
    auto alloc = [&](size_t bytes) { size_t o = off; off = (off + bytes + 255) & ~255ULL; return o; };
    float* deg    = (float*)(w + alloc((size_t)N * 4));
    float* dis    = (float*)(w + alloc((size_t)N * 4));
    int*   cnt    = (int*)(w + alloc((size_t)N * 4));
    int*   fill   = (int*)(w + alloc((size_t)N * 4));
    int*   csr    = (int*)(w + alloc((size_t)(N + 1) * 4));
    int*   packed = (int*)(w + alloc((size_t)E * 4));
    float* snorm  = (float*)(w + alloc((size_t)E * 4));
    unsigned short* xb  = (unsigned short*)(w + alloc((size_t)N * DIM * 2));
    unsigned short* z1b = (unsigned short*)(w + alloc((size_t)N * DIM * 2));
    unsigned short* z2b = (unsigned short*)(w + alloc((size_t)N * DIM * 2));
    float* z1f    = (float*)(w + alloc((size_t)N * DIM * 4));
    float* z2f    = (float*)(w + alloc((size_t)N * DIM * 4));
    unsigned short* Wt1 = (unsigned short*)(w + alloc(65536 * 2));
    unsigned short* Wt2 = (unsigned short*)(w + alloc(65536 * 2));
    unsigned short* Wt3 = (unsigned short*)(w + alloc(65536 * 2));
    unsigned short* agg = (unsigned short*)(w + alloc((size_t)N * 512 * 2));

    hipMemsetAsync(deg, 0, (size_t)N * 4, stream);
    hipMemsetAsync(cnt, 0, (size_t)N * 4, stream);
    hipMemsetAsync(fill, 0, (size_t)N * 4, stream);

    k_deg_cnt<<<(E + 255) / 256, 256, 0, stream>>>(row, col, deg, cnt, E);
    k_dis<<<(N + 255) / 256, 256, 0, stream>>>(deg, dis, N);
    k_scan<<<1, 1024, 0, stream>>>(cnt, csr, N);
    k_scatter<<<(E + 255) / 256, 256, 0, stream>>>(row, col, etype, eattr, dis, csr, fill, packed, snorm, E);
    k_xb<<<(N * DIM / 4 + 255) / 256, 256, 0, stream>>>(x, xb, N * DIM / 4);
    k_wt<<<65536 / 256, 256, 0, stream>>>(W1, Wt1);
    k_wt<<<65536 / 256, 256, 0, stream>>>(W2, Wt2);
    k_wt<<<65536 / 256, 256, 0, stream>>>(W3, Wt3);

    int gemm_grid = (N + 63) / 64;

    // layer 1
    k_agg<<<(N + 3) / 4, 256, 0, stream>>>(xb, csr, packed, snorm, agg, N);
    k_gemm<0><<<gemm_grid, 256, 0, stream>>>(agg, Wt1, b1, nullptr, nullptr, nullptr, z1f, z1b, N);
    // layer 2
    k_agg<<<(N + 3) / 4, 256, 0, stream>>>(z1b, csr, packed, snorm, agg, N);
    k_gemm<0><<<gemm_grid, 256, 0, stream>>>(agg, Wt2, b2, nullptr, nullptr, nullptr, z2f, z2b, N);
    // layer 3 (fused final combine)
    k_agg<<<(N + 3) / 4, 256, 0, stream>>>(z2b, csr, packed, snorm, agg, N);
    k_gemm<1><<<gemm_grid, 256, 0, stream>>>(agg, Wt3, b3, x, z1f, z2f, (float*)d_out, nullptr, N);
}

// Round 3
// 325.918 us; speedup vs baseline: 2.9514x; 2.0015x over previous
//
#include <hip/hip_runtime.h>

#define DIM 128

typedef __attribute__((ext_vector_type(8))) short bf16x8;
typedef __attribute__((ext_vector_type(4))) float f32x4;
typedef unsigned short u16;
typedef unsigned int u32;

__device__ __forceinline__ float bf2f(u32 u) {
    return __builtin_bit_cast(float, u << 16);
}
__device__ __forceinline__ u16 f2bf(float f) {
    u32 u = __builtin_bit_cast(u32, f);
    u = (u + 0x7FFFu + ((u >> 16) & 1u)) >> 16;   // RNE
    return (u16)u;
}

// ---------------- setup kernels ----------------

__global__ void k_deg_cnt(const int* __restrict__ row, const int* __restrict__ col,
                          float* __restrict__ deg, int* __restrict__ cnt, int E) {
    int e = blockIdx.x * blockDim.x + threadIdx.x;
    if (e < E) {
        atomicAdd(&deg[col[e]], 1.0f);
        atomicAdd(&cnt[row[e]], 1);
    }
}

__global__ void k_dis(const float* __restrict__ deg, float* __restrict__ dis, int N) {
    int i = blockIdx.x * blockDim.x + threadIdx.x;
    if (i < N) {
        float d = deg[i];
        dis[i] = d > 0.f ? rsqrtf(d) : 0.f;
    }
}

// hierarchical exclusive scan: scan1 (per-block 1024) -> scan2 (block sums) -> scan3 (add offsets)
__global__ __launch_bounds__(256) void k_scan1(const int* __restrict__ cnt, int* __restrict__ part,
                                               int* __restrict__ bsum, int N) {
    __shared__ int sh[256];
    int b = blockIdx.x, tid = threadIdx.x;
    int base = b * 1024 + tid * 4;
    int4 v = {0, 0, 0, 0};
    if (base + 3 < N) v = *(const int4*)(cnt + base);
    else if (base < N) {
        v.x = cnt[base];
        v.y = base + 1 < N ? cnt[base + 1] : 0;
        v.z = base + 2 < N ? cnt[base + 2] : 0;
        v.w = base + 3 < N ? cnt[base + 3] : 0;
    }
    int s4 = v.x + v.y + v.z + v.w;
    sh[tid] = s4;
    __syncthreads();
    for (int off = 1; off < 256; off <<= 1) {
        int u = tid >= off ? sh[tid - off] : 0;
        __syncthreads();
        sh[tid] += u;
        __syncthreads();
    }
    int ex = sh[tid] - s4;
    if (base < N)     part[base]     = ex;
    if (base + 1 < N) part[base + 1] = ex + v.x;
    if (base + 2 < N) part[base + 2] = ex + v.x + v.y;
    if (base + 3 < N) part[base + 3] = ex + v.x + v.y + v.z;
    if (tid == 255) bsum[b] = sh[255];
}

__global__ void k_scan2(const int* __restrict__ bsum, int* __restrict__ boff,
                        int* __restrict__ csrN, int nb) {
    int l = threadIdx.x;   // one wave
    int v = l < nb ? bsum[l] : 0;
    int orig = v;
    for (int off = 1; off < 64; off <<= 1) {
        int u = __shfl_up(v, off);
        if (l >= off) v += u;
    }
    if (l < nb) boff[l] = v - orig;
    if (l == nb - 1) *csrN = v;
}

__global__ void k_scan3(const int* __restrict__ part, const int* __restrict__ boff,
                        int* __restrict__ csr, int N) {
    int i = blockIdx.x * 256 + threadIdx.x;
    if (i < N) csr[i] = part[i] + boff[i >> 10];
}

__global__ void k_scatter(const int* __restrict__ row, const int* __restrict__ col,
                          const int* __restrict__ et, const float* __restrict__ ew,
                          const float* __restrict__ dis, const int* __restrict__ csr,
                          int* __restrict__ fill, int* __restrict__ packed,
                          float* __restrict__ snorm, int E) {
    int e = blockIdx.x * blockDim.x + threadIdx.x;
    if (e < E) {
        int r = row[e], c = col[e];
        int pos = csr[r] + atomicAdd(&fill[r], 1);
        packed[pos] = c | (et[e] << 16);          // c < 65536 (N=50000)
        snorm[pos] = dis[r] * dis[c] * ew[e];
    }
}

// fp32 -> bf16 node features (x only)
__global__ void k_xb(const float* __restrict__ in, u16* __restrict__ out, int total4) {
    int i = blockIdx.x * blockDim.x + threadIdx.x;
    if (i < total4) {
        float4 v = ((const float4*)in)[i];
        ushort4 o;
        o.x = f2bf(v.x); o.y = f2bf(v.y); o.z = f2bf(v.z); o.w = f2bf(v.w);
        ((ushort4*)out)[i] = o;
    }
}

// W [4][128][128] fp32 -> Wt in MFMA-fragment order: flat o = (k>>3)*1024 + col*8 + (k&7)
// where k = t*128 + i  (K=512), col = output dim n.
__global__ void k_wt(const float* __restrict__ W, u16* __restrict__ Wt) {
    int o = blockIdx.x * blockDim.x + threadIdx.x;   // 65536
    int chunk = o >> 10;
    int col = (o >> 3) & 127;
    int k = chunk * 8 + (o & 7);
    int t = k >> 7, i = k & 127;
    Wt[o] = f2bf(W[t * 16384 + i * 128 + col]);
}

// ---------------- aggregation (bf16 gather, fp32 accum, bf16 agg out), unroll-4 ----------------

__global__ __launch_bounds__(256) void k_agg(const u16* __restrict__ xb,
                                             const int* __restrict__ csr,
                                             const int* __restrict__ packed,
                                             const float* __restrict__ snorm,
                                             u16* __restrict__ agg, int N) {
    int wid = threadIdx.x >> 6;
    int lane = threadIdx.x & 63;
    int n = blockIdx.x * 4 + wid;
    if (n >= N) return;
    float2 a0 = {0.f, 0.f}, a1 = {0.f, 0.f}, a2 = {0.f, 0.f}, a3 = {0.f, 0.f};
    int s = csr[n], e = csr[n + 1];
    const u16* xcol = xb + lane * 2;

#define GATHER(p) (*(const u32*)(xcol + (size_t)((p) & 0xFFFF) * DIM))
#define ACCUM(p, wgt, v) { float v0_ = bf2f((v) & 0xFFFFu) * (wgt), v1_ = bf2f((v) >> 16) * (wgt); \
        int t_ = ((p) >> 16) & 3; \
        if (t_ == 0)      { a0.x += v0_; a0.y += v1_; } \
        else if (t_ == 1) { a1.x += v0_; a1.y += v1_; } \
        else if (t_ == 2) { a2.x += v0_; a2.y += v1_; } \
        else              { a3.x += v0_; a3.y += v1_; } }

    int j = s;
    for (; j + 4 <= e; j += 4) {
        int p0 = packed[j], p1 = packed[j + 1], p2 = packed[j + 2], p3 = packed[j + 3];
        float w0 = snorm[j], w1 = snorm[j + 1], w2 = snorm[j + 2], w3 = snorm[j + 3];
        u32 v0 = GATHER(p0);
        u32 v1 = GATHER(p1);
        u32 v2 = GATHER(p2);
        u32 v3 = GATHER(p3);
        ACCUM(p0, w0, v0); ACCUM(p1, w1, v1); ACCUM(p2, w2, v2); ACCUM(p3, w3, v3);
    }
    for (; j < e; j++) {
        int p = packed[j]; float wg = snorm[j];
        u32 v = GATHER(p);
        ACCUM(p, wg, v);
    }
#undef GATHER
#undef ACCUM

    u32* dst = (u32*)(agg + (size_t)n * 512) + lane;
    dst[0]   = (u32)f2bf(a0.x) | ((u32)f2bf(a0.y) << 16);
    dst[64]  = (u32)f2bf(a1.x) | ((u32)f2bf(a1.y) << 16);
    dst[128] = (u32)f2bf(a2.x) | ((u32)f2bf(a2.y) << 16);
    dst[192] = (u32)f2bf(a3.x) | ((u32)f2bf(a3.y) << 16);
}

// ---------------- MFMA GEMM: leaky(A[rows,512] @ W + bias) ----------------
// A bf16 row-major [rows][512]; Wt bf16 fragment-order (contiguous 16KB per 64-k tile).
// Block: 256 thr / 4 waves, BM=128 (32 rows/wave). B staged in LDS, double-buffered.

template <int MODE>
__global__ __launch_bounds__(256) void k_gemm(const u16* __restrict__ A,
                                              const u16* __restrict__ Wt,
                                              const float* __restrict__ bias,
                                              const float* __restrict__ x0,
                                              const u16* __restrict__ z1b,
                                              const u16* __restrict__ z2b,
                                              float* __restrict__ outf,
                                              u16* __restrict__ outb,
                                              int rows) {
    __shared__ u16 Bs[2][8192];   // 16KB per buffer
    int tid = threadIdx.x, wid = tid >> 6, lane = tid & 63;
    int lr = lane & 15, lk = lane >> 4;
    int row0 = blockIdx.x * 128 + wid * 32;

    int ar0 = row0 + lr;       if (ar0 >= rows) ar0 = rows - 1;
    int ar1 = row0 + 16 + lr;  if (ar1 >= rows) ar1 = rows - 1;
    const u16* A0 = A + (size_t)ar0 * 512 + lk * 8;
    const u16* A1 = A + (size_t)ar1 * 512 + lk * 8;

    f32x4 acc[2][8] = {};

    // stage k-tile kt into Bs[buf]: contiguous 16KB copy, linear LDS dest
    auto stage = [&](int kt, int buf) {
        const u16* g = Wt + kt * 8192 + wid * 2048 + lane * 8;
        u16* l = &Bs[buf][wid * 2048];
        #pragma unroll
        for (int i = 0; i < 4; i++)
            __builtin_amdgcn_global_load_lds(
                (const __attribute__((address_space(1))) u32*)(g + i * 512),
                (__attribute__((address_space(3))) u32*)(l + i * 512), 16, 0, 0);
    };

    stage(0, 0);
    __syncthreads();
    for (int kt = 0; kt < 8; kt++) {
        int cur = kt & 1;
        if (kt < 7) stage(kt + 1, cur ^ 1);
        const u16* base = &Bs[cur][0];
        #pragma unroll
        for (int half = 0; half < 2; half++) {
            bf16x8 af0 = *(const bf16x8*)(A0 + kt * 64 + half * 32);
            bf16x8 af1 = *(const bf16x8*)(A1 + kt * 64 + half * 32);
            int chunk = half * 4 + lk;
            #pragma unroll
            for (int ct = 0; ct < 8; ct++) {
                bf16x8 bfv = *(const bf16x8*)(base + chunk * 1024 + (ct * 16 + lr) * 8);
                acc[0][ct] = __builtin_amdgcn_mfma_f32_16x16x32_bf16(af0, bfv, acc[0][ct], 0, 0, 0);
                acc[1][ct] = __builtin_amdgcn_mfma_f32_16x16x32_bf16(af1, bfv, acc[1][ct], 0, 0, 0);
            }
        }
        __syncthreads();
    }

    // epilogue: C/D layout col = lane&15, row = (lane>>4)*4 + reg
    #pragma unroll
    for (int rf = 0; rf < 2; rf++) {
        #pragma unroll
        for (int ct = 0; ct < 8; ct++) {
            int col = ct * 16 + lr;
            float bv = bias[col];
            #pragma unroll
            for (int r = 0; r < 4; r++) {
                int rowv = row0 + rf * 16 + lk * 4 + r;
                if (rowv < rows) {
                    size_t idx = (size_t)rowv * DIM + col;
                    float v = acc[rf][ct][r] + bv;
                    v = v > 0.f ? v : 0.01f * v;
                    if (MODE == 1)
                        outf[idx] = 0.25f * (x0[idx] + bf2f(z1b[idx]) + bf2f(z2b[idx]) + v);
                    else
                        outb[idx] = f2bf(v);
                }
            }
        }
    }
}

// ---------------- launch ----------------

extern "C" void kernel_launch(void* const* d_in, const int* in_sizes, int n_in,
                              void* d_out, int out_size, void* d_ws, size_t ws_size,
                              hipStream_t stream) {
    const float* x     = (const float*)d_in[0];
    const int*   eidx  = (const int*)d_in[1];
    const int*   etype = (const int*)d_in[2];
    const float* eattr = (const float*)d_in[3];
    const float* W1 = (const float*)d_in[4];
    const float* b1 = (const float*)d_in[5];
    const float* W2 = (const float*)d_in[6];
    const float* b2 = (const float*)d_in[7];
    const float* W3 = (const float*)d_in[8];
    const float* b3 = (const float*)d_in[9];

    const int E = in_sizes[2];
    const int N = in_sizes[0] / DIM;
    const int* row = eidx;
    const int* col = eidx + E;

    char* w = (char*)d_ws;
    size_t off = 0;
    auto alloc = [&](size_t bytes) { size_t o = off; off = (off + bytes + 255) & ~255ULL; return o; };
    float* deg    = (float*)(w + alloc((size_t)N * 4));
    float* dis    = (float*)(w + alloc((size_t)N * 4));
    int*   cnt    = (int*)(w + alloc((size_t)N * 4));
    int*   fill   = (int*)(w + alloc((size_t)N * 4));
    int*   csr    = (int*)(w + alloc((size_t)(N + 1) * 4));
    int*   part   = (int*)(w + alloc((size_t)N * 4));
    int*   bsum   = (int*)(w + alloc(256 * 4));
    int*   boff   = (int*)(w + alloc(256 * 4));
    int*   packed = (int*)(w + alloc((size_t)E * 4));
    float* snorm  = (float*)(w + alloc((size_t)E * 4));
    u16*   xb     = (u16*)(w + alloc((size_t)N * DIM * 2));
    u16*   z1b    = (u16*)(w + alloc((size_t)N * DIM * 2));
    u16*   z2b    = (u16*)(w + alloc((size_t)N * DIM * 2));
    u16*   Wt1    = (u16*)(w + alloc(65536 * 2));
    u16*   Wt2    = (u16*)(w + alloc(65536 * 2));
    u16*   Wt3    = (u16*)(w + alloc(65536 * 2));
    u16*   agg    = (u16*)(w + alloc((size_t)N * 512 * 2));

    hipMemsetAsync(deg, 0, (size_t)N * 4, stream);
    hipMemsetAsync(cnt, 0, (size_t)N * 4, stream);
    hipMemsetAsync(fill, 0, (size_t)N * 4, stream);

    int nb = (N + 1023) / 1024;   // 49

    k_deg_cnt<<<(E + 255) / 256, 256, 0, stream>>>(row, col, deg, cnt, E);
    k_dis<<<(N + 255) / 256, 256, 0, stream>>>(deg, dis, N);
    k_scan1<<<nb, 256, 0, stream>>>(cnt, part, bsum, N);
    k_scan2<<<1, 64, 0, stream>>>(bsum, boff, csr + N, nb);
    k_scan3<<<(N + 255) / 256, 256, 0, stream>>>(part, boff, csr, N);
    k_scatter<<<(E + 255) / 256, 256, 0, stream>>>(row, col, etype, eattr, dis, csr, fill, packed, snorm, E);
    k_xb<<<(N * DIM / 4 + 255) / 256, 256, 0, stream>>>(x, xb, N * DIM / 4);
    k_wt<<<65536 / 256, 256, 0, stream>>>(W1, Wt1);
    k_wt<<<65536 / 256, 256, 0, stream>>>(W2, Wt2);
    k_wt<<<65536 / 256, 256, 0, stream>>>(W3, Wt3);

    int gemm_grid = (N + 127) / 128;

    // layer 1
    k_agg<<<(N + 3) / 4, 256, 0, stream>>>(xb, csr, packed, snorm, agg, N);
    k_gemm<0><<<gemm_grid, 256, 0, stream>>>(agg, Wt1, b1, nullptr, nullptr, nullptr, nullptr, z1b, N);
    // layer 2
    k_agg<<<(N + 3) / 4, 256, 0, stream>>>(z1b, csr, packed, snorm, agg, N);
    k_gemm<0><<<gemm_grid, 256, 0, stream>>>(agg, Wt2, b2, nullptr, nullptr, nullptr, nullptr, z2b, N);
    // layer 3 (fused final combine, fp32 out)
    k_agg<<<(N + 3) / 4, 256, 0, stream>>>(z2b, csr, packed, snorm, agg, N);
    k_gemm<1><<<gemm_grid, 256, 0, stream>>>(agg, Wt3, b3, x, z1b, z2b, (float*)d_out, nullptr, N);
}

// Round 4
// 300.595 us; speedup vs baseline: 3.2000x; 1.0842x over previous
//
#include <hip/hip_runtime.h>

#define DIM 128

typedef __attribute__((ext_vector_type(8))) short bf16x8;
typedef __attribute__((ext_vector_type(4))) float f32x4;
typedef unsigned short u16;
typedef unsigned int u32;
typedef unsigned long long u64;

__device__ __forceinline__ float bf2f(u32 u) {
    return __builtin_bit_cast(float, u << 16);
}
__device__ __forceinline__ u16 f2bf(float f) {
    u32 u = __builtin_bit_cast(u32, f);
    u = (u + 0x7FFFu + ((u >> 16) & 1u)) >> 16;   // RNE
    return (u16)u;
}

// ---------------- fused setup: deg/cnt atomics + x->bf16 + Wt build x3 ----------------

__global__ __launch_bounds__(256) void k_setup(const int* __restrict__ row, const int* __restrict__ col,
                                               int E, float* __restrict__ deg, int* __restrict__ cnt,
                                               const float* __restrict__ x, u16* __restrict__ xb, int nx4,
                                               const float* __restrict__ W1, const float* __restrict__ W2,
                                               const float* __restrict__ W3,
                                               u16* __restrict__ Wt1, u16* __restrict__ Wt2,
                                               u16* __restrict__ Wt3, int nEb, int nXb) {
    int b = blockIdx.x, tid = threadIdx.x;
    if (b < nEb) {
        int e = b * 256 + tid;
        if (e < E) {
            atomicAdd(&deg[col[e]], 1.0f);
            atomicAdd(&cnt[row[e]], 1);
        }
    } else if (b < nEb + nXb) {
        int i = (b - nEb) * 256 + tid;
        if (i < nx4) {
            float4 v = ((const float4*)x)[i];
            ushort4 o;
            o.x = f2bf(v.x); o.y = f2bf(v.y); o.z = f2bf(v.z); o.w = f2bf(v.w);
            ((ushort4*)xb)[i] = o;
        }
    } else {
        int b2 = b - nEb - nXb;                    // 0..767
        const float* W = b2 < 256 ? W1 : (b2 < 512 ? W2 : W3);
        u16* Wt = b2 < 256 ? Wt1 : (b2 < 512 ? Wt2 : Wt3);
        int o = (b2 & 255) * 256 + tid;            // 0..65535
        // fragment order: o = (k>>3)*1024 + col*8 + (k&7)
        int chunk = o >> 10;
        int c = (o >> 3) & 127;
        int k = chunk * 8 + (o & 7);
        Wt[o] = f2bf(W[(k >> 7) * 16384 + (k & 127) * 128 + c]);
    }
}

__global__ void k_dis(const float* __restrict__ deg, float* __restrict__ dis, int N) {
    int i = blockIdx.x * blockDim.x + threadIdx.x;
    if (i < N) {
        float d = deg[i];
        dis[i] = d > 0.f ? rsqrtf(d) : 0.f;
    }
}

// hierarchical exclusive scan
__global__ __launch_bounds__(256) void k_scan1(const int* __restrict__ cnt, int* __restrict__ part,
                                               int* __restrict__ bsum, int N) {
    __shared__ int sh[256];
    int b = blockIdx.x, tid = threadIdx.x;
    int base = b * 1024 + tid * 4;
    int4 v = {0, 0, 0, 0};
    if (base + 3 < N) v = *(const int4*)(cnt + base);
    else if (base < N) {
        v.x = cnt[base];
        v.y = base + 1 < N ? cnt[base + 1] : 0;
        v.z = base + 2 < N ? cnt[base + 2] : 0;
        v.w = base + 3 < N ? cnt[base + 3] : 0;
    }
    int s4 = v.x + v.y + v.z + v.w;
    sh[tid] = s4;
    __syncthreads();
    for (int off = 1; off < 256; off <<= 1) {
        int u = tid >= off ? sh[tid - off] : 0;
        __syncthreads();
        sh[tid] += u;
        __syncthreads();
    }
    int ex = sh[tid] - s4;
    if (base < N)     part[base]     = ex;
    if (base + 1 < N) part[base + 1] = ex + v.x;
    if (base + 2 < N) part[base + 2] = ex + v.x + v.y;
    if (base + 3 < N) part[base + 3] = ex + v.x + v.y + v.z;
    if (tid == 255) bsum[b] = sh[255];
}

__global__ void k_scan2(const int* __restrict__ bsum, int* __restrict__ boff,
                        int* __restrict__ csrN, int nb) {
    int l = threadIdx.x;
    int v = l < nb ? bsum[l] : 0;
    int orig = v;
    for (int off = 1; off < 64; off <<= 1) {
        int u = __shfl_up(v, off);
        if (l >= off) v += u;
    }
    if (l < nb) boff[l] = v - orig;
    if (l == nb - 1) *csrN = v;
}

__global__ void k_scan3(const int* __restrict__ part, const int* __restrict__ boff,
                        int* __restrict__ csr, int N) {
    int i = blockIdx.x * 256 + threadIdx.x;
    if (i < N) csr[i] = part[i] + boff[i >> 10];
}

// scatter edges into CSR order; (packed, snorm) paired in one u64
__global__ void k_scatter(const int* __restrict__ row, const int* __restrict__ col,
                          const int* __restrict__ et, const float* __restrict__ ew,
                          const float* __restrict__ dis, const int* __restrict__ csr,
                          int* __restrict__ fill, u64* __restrict__ ep, int E) {
    int e = blockIdx.x * blockDim.x + threadIdx.x;
    if (e < E) {
        int r = row[e], c = col[e];
        int pos = csr[r] + atomicAdd(&fill[r], 1);
        float sn = dis[r] * dis[c] * ew[e];
        ep[pos] = ((u64)__builtin_bit_cast(u32, sn) << 32) | (u32)(c | (et[e] << 16));
    }
}

// ---------------- fused layer: gather-aggregate (registers) -> LDS -> MFMA -> epilogue ----------------
// block = 256 thr / 4 waves = 16 nodes. LDS agg tile [16][512] bf16, XOR-swizzled.

template <int MODE>
__global__ __launch_bounds__(256) void k_layer(const u16* __restrict__ src,
                                               const int* __restrict__ csr,
                                               const u64* __restrict__ ep,
                                               const u16* __restrict__ Wt,
                                               const float* __restrict__ bias,
                                               const float* __restrict__ x0,
                                               const u16* __restrict__ z1b,
                                               const u16* __restrict__ z2b,
                                               float* __restrict__ outf,
                                               u16* __restrict__ outb, int N) {
    __shared__ u16 sA[16 * 512];   // 16 KB
    int tid = threadIdx.x, wid = tid >> 6, lane = tid & 63;
    int n0 = blockIdx.x * 16;

    // ---- gather phase: 4 nodes per wave, sequential; lane covers cols 2*lane, 2*lane+1 ----
    const u16* xcol = src + lane * 2;
    for (int i = 0; i < 4; i++) {
        int n = n0 + wid * 4 + i;
        float2 a0 = {0.f, 0.f}, a1 = {0.f, 0.f}, a2 = {0.f, 0.f}, a3 = {0.f, 0.f};
        if (n < N) {
            int s = csr[n], e = csr[n + 1];
#define ACC(q, v) { float wgt_ = __builtin_bit_cast(float, (u32)((q) >> 32)); \
        float v0_ = bf2f((v) & 0xFFFFu) * wgt_, v1_ = bf2f((v) >> 16) * wgt_; \
        int t_ = (int)(((q) >> 16) & 3); \
        if (t_ == 0)      { a0.x += v0_; a0.y += v1_; } \
        else if (t_ == 1) { a1.x += v0_; a1.y += v1_; } \
        else if (t_ == 2) { a2.x += v0_; a2.y += v1_; } \
        else              { a3.x += v0_; a3.y += v1_; } }
            int j = s;
            for (; j + 4 <= e; j += 4) {
                u64 q0 = ep[j], q1 = ep[j + 1], q2 = ep[j + 2], q3 = ep[j + 3];
                u32 v0 = *(const u32*)(xcol + (size_t)(q0 & 0xFFFF) * DIM);
                u32 v1 = *(const u32*)(xcol + (size_t)(q1 & 0xFFFF) * DIM);
                u32 v2 = *(const u32*)(xcol + (size_t)(q2 & 0xFFFF) * DIM);
                u32 v3 = *(const u32*)(xcol + (size_t)(q3 & 0xFFFF) * DIM);
                ACC(q0, v0); ACC(q1, v1); ACC(q2, v2); ACC(q3, v3);
            }
            for (; j < e; j++) {
                u64 q = ep[j];
                u32 v = *(const u32*)(xcol + (size_t)(q & 0xFFFF) * DIM);
                ACC(q, v);
            }
#undef ACC
        }
        // write LDS agg row r (k = t*128 + 2*lane), swizzled byte ^= (r&7)<<4
        int r = wid * 4 + i;
        u32 X = (u32)((r & 7) << 4);
        char* base = (char*)sA + r * 1024;
        *(u32*)(base + ((lane * 4 + 0  ) ^ X)) = (u32)f2bf(a0.x) | ((u32)f2bf(a0.y) << 16);
        *(u32*)(base + ((lane * 4 + 256) ^ X)) = (u32)f2bf(a1.x) | ((u32)f2bf(a1.y) << 16);
        *(u32*)(base + ((lane * 4 + 512) ^ X)) = (u32)f2bf(a2.x) | ((u32)f2bf(a2.y) << 16);
        *(u32*)(base + ((lane * 4 + 768) ^ X)) = (u32)f2bf(a3.x) | ((u32)f2bf(a3.y) << 16);
    }
    __syncthreads();

    // ---- MFMA phase: [16,512] @ [512,128]; wave w -> cols 32w..32w+31 ----
    int lr = lane & 15, lk = lane >> 4;
    u32 XR = (u32)((lr & 7) << 4);
    const char* abase = (const char*)sA + lr * 1024;
    const u16* bbase = Wt + lk * 1024 + (wid * 32 + lr) * 8;
    f32x4 acc0 = {}, acc1 = {};
    #pragma unroll
    for (int ks = 0; ks < 16; ks++) {
        bf16x8 af = *(const bf16x8*)(abase + ((ks * 64 + lk * 16) ^ XR));
        bf16x8 b0 = *(const bf16x8*)(bbase + ks * 4096);
        bf16x8 b1 = *(const bf16x8*)(bbase + ks * 4096 + 128);
        acc0 = __builtin_amdgcn_mfma_f32_16x16x32_bf16(af, b0, acc0, 0, 0, 0);
        acc1 = __builtin_amdgcn_mfma_f32_16x16x32_bf16(af, b1, acc1, 0, 0, 0);
    }

    // ---- epilogue: C/D layout col = lane&15 (+ct*16), row = (lane>>4)*4 + r ----
    #pragma unroll
    for (int ct = 0; ct < 2; ct++) {
        f32x4 a = ct ? acc1 : acc0;
        int colg = wid * 32 + ct * 16 + lr;
        float bv = bias[colg];
        #pragma unroll
        for (int r = 0; r < 4; r++) {
            int n = n0 + lk * 4 + r;
            if (n < N) {
                size_t idx = (size_t)n * DIM + colg;
                float v = a[r] + bv;
                v = v > 0.f ? v : 0.01f * v;
                if (MODE == 1)
                    outf[idx] = 0.25f * (x0[idx] + bf2f(z1b[idx]) + bf2f(z2b[idx]) + v);
                else
                    outb[idx] = f2bf(v);
            }
        }
    }
}

// ---------------- launch ----------------

extern "C" void kernel_launch(void* const* d_in, const int* in_sizes, int n_in,
                              void* d_out, int out_size, void* d_ws, size_t ws_size,
                              hipStream_t stream) {
    const float* x     = (const float*)d_in[0];
    const int*   eidx  = (const int*)d_in[1];
    const int*   etype = (const int*)d_in[2];
    const float* eattr = (const float*)d_in[3];
    const float* W1 = (const float*)d_in[4];
    const float* b1 = (const float*)d_in[5];
    const float* W2 = (const float*)d_in[6];
    const float* b2 = (const float*)d_in[7];
    const float* W3 = (const float*)d_in[8];
    const float* b3 = (const float*)d_in[9];

    const int E = in_sizes[2];
    const int N = in_sizes[0] / DIM;
    const int* row = eidx;
    const int* col = eidx + E;

    char* w = (char*)d_ws;
    size_t off = 0;
    auto alloc = [&](size_t bytes) { size_t o = off; off = (off + bytes + 255) & ~255ULL; return o; };
    // deg, cnt, fill contiguous -> single memset
    size_t deg_off = alloc((size_t)N * 4);
    float* deg    = (float*)(w + deg_off);
    int*   cnt    = (int*)(w + alloc((size_t)N * 4));
    int*   fill   = (int*)(w + alloc((size_t)N * 4));
    size_t zero_bytes = off - deg_off;
    float* dis    = (float*)(w + alloc((size_t)N * 4));
    int*   csr    = (int*)(w + alloc((size_t)(N + 1) * 4));
    int*   part   = (int*)(w + alloc((size_t)N * 4));
    int*   bsum   = (int*)(w + alloc(256 * 4));
    int*   boff   = (int*)(w + alloc(256 * 4));
    u64*   ep     = (u64*)(w + alloc((size_t)E * 8));
    u16*   xb     = (u16*)(w + alloc((size_t)N * DIM * 2));
    u16*   z1b    = (u16*)(w + alloc((size_t)N * DIM * 2));
    u16*   z2b    = (u16*)(w + alloc((size_t)N * DIM * 2));
    u16*   Wt1    = (u16*)(w + alloc(65536 * 2));
    u16*   Wt2    = (u16*)(w + alloc(65536 * 2));
    u16*   Wt3    = (u16*)(w + alloc(65536 * 2));

    hipMemsetAsync(deg, 0, zero_bytes, stream);

    int nx4 = N * DIM / 4;
    int nEb = (E + 255) / 256;
    int nXb = (nx4 + 255) / 256;
    int nb  = (N + 1023) / 1024;

    k_setup<<<nEb + nXb + 768, 256, 0, stream>>>(row, col, E, deg, cnt, x, xb, nx4,
                                                 W1, W2, W3, Wt1, Wt2, Wt3, nEb, nXb);
    k_dis<<<(N + 255) / 256, 256, 0, stream>>>(deg, dis, N);
    k_scan1<<<nb, 256, 0, stream>>>(cnt, part, bsum, N);
    k_scan2<<<1, 64, 0, stream>>>(bsum, boff, csr + N, nb);
    k_scan3<<<(N + 255) / 256, 256, 0, stream>>>(part, boff, csr, N);
    k_scatter<<<(E + 255) / 256, 256, 0, stream>>>(row, col, etype, eattr, dis, csr, fill, ep, E);

    int grid = (N + 15) / 16;
    k_layer<0><<<grid, 256, 0, stream>>>(xb,  csr, ep, Wt1, b1, nullptr, nullptr, nullptr, nullptr, z1b, N);
    k_layer<0><<<grid, 256, 0, stream>>>(z1b, csr, ep, Wt2, b2, nullptr, nullptr, nullptr, nullptr, z2b, N);
    k_layer<1><<<grid, 256, 0, stream>>>(z2b, csr, ep, Wt3, b3, x, z1b, z2b, (float*)d_out, nullptr, N);
}